// Round 1
// baseline (1478.370 us; speedup 1.0000x reference)
//
#include <hip/hip_runtime.h>

typedef unsigned short u16;
typedef __bf16 bf16x8 __attribute__((ext_vector_type(8)));
typedef float  f32x4  __attribute__((ext_vector_type(4)));
typedef u16    u16x8  __attribute__((ext_vector_type(8)));

// ---------- problem constants ----------
#define BATCH 256
#define TT    197          // tokens
#define TP    256          // padded tokens (attention)
#define DD    192          // model dim
#define DHP   64           // padded head dim (real 48)
#define MTOK  (BATCH*TT)   // 50432 rows, divisible by 64
#define MPAT  (BATCH*196)  // 50176 rows, divisible by 64

constexpr size_t BIG_E  = 1024ull*256*256;   // S buffer (also patches 38.5M, mlp-h 38.7M)
constexpr size_t TOK_E  = (size_t)MTOK*DD;
constexpr size_t QKV_E  = 1024ull*TP*DHP;    // per q/k/v tensor
constexpr size_t VT_E   = 1024ull*DHP*TP;

__device__ __forceinline__ float b2f(u16 h){ union{unsigned u; float f;} x; x.u=(unsigned)h<<16; return x.f; }
__device__ __forceinline__ u16 f2b(float f){ union{float f; unsigned u;} x{f}; unsigned r = x.u + 0x7fffu + ((x.u>>16)&1u); return (u16)(r>>16); }

__device__ __forceinline__ void gload_lds16(const void* g, void* l) {
  __builtin_amdgcn_global_load_lds((__attribute__((address_space(1))) void*)(size_t)g,
                                   (__attribute__((address_space(3))) void*)l, 16, 0, 0);
}

// ---------- generic 1-wave 64x64 MFMA GEMM:  C = A(MxK) @ W(NxK)^T ----------
enum { M_F32=0, M_BF16=1, M_QKV=2, M_PV=3, M_PATCH=4 };

template<int MODE, bool RELU, bool RES, bool BIAS>
__global__ __launch_bounds__(64)
void gemm1w(const u16* __restrict__ A, const u16* __restrict__ W,
            const float* __restrict__ bias, const u16* __restrict__ res,
            void* __restrict__ Cout, const float* __restrict__ aux,
            int K, int lda, int ldc, int Nreal,
            long bA, long bW, long bC)
{
  __shared__ __align__(16) u16 As[64*32];
  __shared__ __align__(16) u16 Ws[64*32];
  const int lane = threadIdx.x;
  const int m0 = blockIdx.x * 64;
  const int n0 = blockIdx.y * 64;
  const int bz = blockIdx.z;
  const u16* Ab = A + (size_t)bz * (size_t)bA;
  const u16* Wb = W + (size_t)bz * (size_t)bW;

  const int lrow = lane & 15, quad = lane >> 4;
  const int srow = lane >> 2, sseg = lane & 3;   // staging: 16 rows x 4 x 16B per issue

  f32x4 acc[4][4];
  #pragma unroll
  for (int i=0;i<4;i++)
    #pragma unroll
    for (int j=0;j<4;j++) { f32x4 z = {0.f,0.f,0.f,0.f}; acc[i][j] = z; }

  for (int k0 = 0; k0 < K; k0 += 32) {
    __syncthreads();
    #pragma unroll
    for (int i=0;i<4;i++) {
      const u16* ga = Ab + (size_t)(m0 + i*16 + srow)*lda + (k0 + sseg*8);
      gload_lds16(ga, &As[i*16*32]);
      const u16* gw = Wb + (size_t)(n0 + i*16 + srow)*K + (k0 + sseg*8);
      gload_lds16(gw, &Ws[i*16*32]);
    }
    __builtin_amdgcn_s_waitcnt(0);
    __syncthreads();
    bf16x8 af[4], wf[4];
    #pragma unroll
    for (int i=0;i<4;i++) {
      af[i] = *(const bf16x8*)&As[(i*16 + lrow)*32 + quad*8];
      wf[i] = *(const bf16x8*)&Ws[(i*16 + lrow)*32 + quad*8];
    }
    #pragma unroll
    for (int mi=0;mi<4;mi++)
      #pragma unroll
      for (int ni=0;ni<4;ni++)
        acc[mi][ni] = __builtin_amdgcn_mfma_f32_16x16x32_bf16(af[mi], wf[ni], acc[mi][ni], 0,0,0);
  }

  // epilogue: C/D layout col = lane&15, row = quad*4 + r
  #pragma unroll
  for (int mi=0;mi<4;mi++) {
    #pragma unroll
    for (int ni=0;ni<4;ni++) {
      #pragma unroll
      for (int r=0;r<4;r++) {
        int row = m0 + mi*16 + quad*4 + r;
        int col = n0 + ni*16 + lrow;
        float v = acc[mi][ni][r];
        if constexpr (MODE == M_F32) {
          if (col < Nreal) {
            if constexpr (BIAS) v += bias[col];
            ((float*)Cout)[(size_t)row*ldc + col] = v;
          }
        } else if constexpr (MODE == M_BF16) {
          if constexpr (BIAS) v += bias[col];
          if constexpr (RES)  v += b2f(res[(size_t)row*ldc + col]);
          if constexpr (RELU) v = v > 0.f ? v : 0.f;
          ((u16*)Cout)[(size_t)bz*(size_t)bC + (size_t)row*ldc + col] = f2b(v);
        } else if constexpr (MODE == M_QKV) {
          v += bias[col];
          int sel = col / 192, rem = col % 192;
          int h = rem / 48, d = rem % 48;
          int b = row / 197, t = row % 197;
          ((u16*)Cout)[(size_t)sel*QKV_E + ((size_t)(b*4 + h)*TP + t)*DHP + d] = f2b(v);
        } else if constexpr (MODE == M_PV) {
          if (col < 48 && row < 197) {
            int b = bz >> 2, h = bz & 3;
            ((u16*)Cout)[((size_t)(b*197) + row)*DD + h*48 + col] = f2b(v);
          }
        } else if constexpr (MODE == M_PATCH) {
          int b = row / 196, p = row % 196;
          v += bias[col] + aux[(size_t)(1 + p)*DD + col];
          ((u16*)Cout)[((size_t)(b*197) + 1 + p)*DD + col] = f2b(v);
        }
      }
    }
  }
}

// ---------- small kernels ----------
__global__ void cvt_k(const float* __restrict__ s, u16* __restrict__ d, int n) {
  int i = blockIdx.x*256 + threadIdx.x;
  if (i < n) d[i] = f2b(s[i]);
}

// im2col + fp32->bf16: patches[(b*196+pr*14+pc)*768 + c*256+i*16+j]
__global__ void im2col_k(const float* __restrict__ x, u16* __restrict__ P) {
  int id = blockIdx.x*256 + threadIdx.x;      // 256*3*224*28 threads exactly
  int w8 = id % 28; int r = id / 28;
  int h  = r % 224; r /= 224;
  int c  = r % 3;   int b = r / 3;
  const float* src = x + (((size_t)(b*3 + c)*224 + h)*224 + w8*8);
  float4 a  = *(const float4*)src;
  float4 bb = *(const float4*)(src + 4);
  int pr = h >> 4, i = h & 15, pc = (w8*8) >> 4, j0 = (w8*8) & 15;
  u16* dst = P + ((size_t)(b*196) + pr*14 + pc)*768 + (c*256 + i*16 + j0);
  u16x8 o;
  o[0]=f2b(a.x); o[1]=f2b(a.y); o[2]=f2b(a.z); o[3]=f2b(a.w);
  o[4]=f2b(bb.x); o[5]=f2b(bb.y); o[6]=f2b(bb.z); o[7]=f2b(bb.w);
  *(u16x8*)dst = o;
}

__global__ void cls_k(const float* __restrict__ cls_tok, const float* __restrict__ pos, u16* __restrict__ tok) {
  int b = blockIdx.x, d = threadIdx.x;
  tok[((size_t)b*197)*DD + d] = f2b(cls_tok[d] + pos[d]);
}

// W_eff[i][p*192+n][k] = sum_m in_w[i][p*192+n][m] * {q,k,v}_w[i][m][k]
__global__ void fusew_k(const float* __restrict__ in_w, const float* __restrict__ q_w,
                        const float* __restrict__ k_w, const float* __restrict__ v_w,
                        u16* __restrict__ weff) {
  int i = blockIdx.x, p = blockIdx.y, n = blockIdx.z;
  int k = threadIdx.x;
  const float* wrow = in_w + ((size_t)i*576 + p*192 + n)*192;
  const float* Bm = (p==0 ? q_w : (p==1 ? k_w : v_w)) + (size_t)i*192*192;
  float acc = 0.f;
  for (int m=0;m<192;m++) acc += wrow[m] * Bm[m*192 + k];
  weff[((size_t)i*576 + p*192 + n)*192 + k] = f2b(acc);
}

// b_eff[i][n] = sum_m in_w[i][n][m]*{q,k,v}_b[i][m] + in_b[i][n]
__global__ void fuseb_k(const float* __restrict__ in_w, const float* __restrict__ q_b,
                        const float* __restrict__ k_b, const float* __restrict__ v_b,
                        const float* __restrict__ in_b, float* __restrict__ effb) {
  int i = blockIdx.x, n = threadIdx.x;
  int p = n / 192;
  const float* bb = (p==0 ? q_b : (p==1 ? k_b : v_b)) + i*192;
  const float* wrow = in_w + ((size_t)i*576 + n)*192;
  float acc = in_b[i*576 + n];
  for (int m=0;m<192;m++) acc += wrow[m]*bb[m];
  effb[i*576 + n] = acc;
}

// V (1024,TP,DHP) -> Vt (1024,DHP,TP)
__global__ void vtrans_k(const u16* __restrict__ V, u16* __restrict__ Vt) {
  int bz = blockIdx.x, tc = blockIdx.y, dq = blockIdx.z;
  int t = tc*64 + threadIdx.x;
  if (t >= 197) return;
  u16x8 val = *(const u16x8*)(V + ((size_t)bz*TP + t)*DHP + dq*8);
  u16* dst = Vt + (size_t)bz*DHP*TP + (size_t)(dq*8)*TP + t;
  #pragma unroll
  for (int j=0;j<8;j++) dst[(size_t)j*TP] = val[j];
}

// softmax over k (<197) with scale folded in; zero cols 197..255; wave per row
__global__ void softmax_k(u16* __restrict__ S) {
  int bz = blockIdx.x;
  int wave = threadIdx.x >> 6, lane = threadIdx.x & 63;
  int t = blockIdx.y*4 + wave;
  if (t >= 197) return;
  u16* row = S + ((size_t)bz*TP + t)*TP;
  const float scale = 0.14433756729740643f;   // 1/sqrt(48)
  float v[4];
  #pragma unroll
  for (int j=0;j<4;j++) {
    int c = lane + j*64;
    v[j] = (c < 197) ? b2f(row[c]) : -1e30f;
  }
  float mx = fmaxf(fmaxf(v[0],v[1]), fmaxf(v[2],v[3]));
  #pragma unroll
  for (int s=32; s; s>>=1) mx = fmaxf(mx, __shfl_xor(mx, s, 64));
  float e[4]; float sum = 0.f;
  #pragma unroll
  for (int j=0;j<4;j++) {
    int c = lane + j*64;
    e[j] = (c < 197) ? __expf((v[j]-mx)*scale) : 0.f;
    sum += e[j];
  }
  #pragma unroll
  for (int s=32; s; s>>=1) sum += __shfl_xor(sum, s, 64);
  float inv = 1.f / sum;
  #pragma unroll
  for (int j=0;j<4;j++) row[lane + j*64] = f2b(e[j]*inv);
}

// ---------- orchestration ----------
extern "C" void kernel_launch(void* const* d_in, const int* in_sizes, int n_in,
                              void* d_out, int out_size, void* d_ws, size_t ws_size,
                              hipStream_t stream) {
  const float* x      = (const float*)d_in[0];
  const float* lm_w   = (const float*)d_in[1];
  const float* lm_b   = (const float*)d_in[2];
  const float* cls_t  = (const float*)d_in[3];
  const float* pos    = (const float*)d_in[4];
  const float* q_w    = (const float*)d_in[5];
  const float* q_b    = (const float*)d_in[6];
  const float* k_w    = (const float*)d_in[7];
  const float* k_b    = (const float*)d_in[8];
  const float* v_w    = (const float*)d_in[9];
  const float* v_b    = (const float*)d_in[10];
  const float* in_w   = (const float*)d_in[11];
  const float* in_b   = (const float*)d_in[12];
  const float* out_w  = (const float*)d_in[13];
  const float* out_b  = (const float*)d_in[14];
  const float* up_w   = (const float*)d_in[15];
  const float* up_b   = (const float*)d_in[16];
  const float* dn_w   = (const float*)d_in[17];
  const float* dn_b   = (const float*)d_in[18];
  const float* head_w = (const float*)d_in[19];
  const float* head_b = (const float*)d_in[20];

  char* ws = (char*)d_ws;
  size_t off = 0;
  auto alloc = [&](size_t elems, size_t esz) {
    void* p = ws + off; off += ((elems*esz + 255)/256)*256; return p;
  };
  u16*  big  = (u16*)alloc(BIG_E, 2);        // patches / S / mlp hidden
  u16*  tok  = (u16*)alloc(TOK_E, 2);
  u16*  qq   = (u16*)alloc(QKV_E*3, 2);      // q,k,v contiguous
  u16*  vt   = (u16*)alloc(VT_E, 2);
  u16*  obuf = (u16*)alloc(TOK_E, 2);
  u16*  lmw  = (u16*)alloc(147456, 2);
  u16*  outw = (u16*)alloc(110592, 2);
  u16*  upw  = (u16*)alloc(442368, 2);
  u16*  dnw  = (u16*)alloc(442368, 2);
  u16*  hdw  = (u16*)alloc(196608, 2);       // head_w padded to 1024 rows
  u16*  weff = (u16*)alloc(331776, 2);
  float* effb = (float*)alloc(1728, 4);
  (void)ws_size; (void)in_sizes; (void)n_in; (void)out_size;

  u16* kbuf = qq + QKV_E;
  u16* vbuf = qq + 2*QKV_E;

  // weight prep
  cvt_k<<<(147456+255)/256,256,0,stream>>>(lm_w,  lmw, 147456);
  cvt_k<<<(110592+255)/256,256,0,stream>>>(out_w, outw, 110592);
  cvt_k<<<(442368+255)/256,256,0,stream>>>(up_w,  upw, 442368);
  cvt_k<<<(442368+255)/256,256,0,stream>>>(dn_w,  dnw, 442368);
  cvt_k<<<(192000+255)/256,256,0,stream>>>(head_w,hdw, 192000);
  hipMemsetAsync(hdw + 192000, 0, (196608-192000)*2, stream);
  fusew_k<<<dim3(3,3,192),192,0,stream>>>(in_w, q_w, k_w, v_w, weff);
  fuseb_k<<<3,576,0,stream>>>(in_w, q_b, k_b, v_b, in_b, effb);

  // patch embed + pos + cls
  im2col_k<<<18816,256,0,stream>>>(x, big);
  gemm1w<M_PATCH,false,false,true><<<dim3(MPAT/64,3,1),64,0,stream>>>(
      big, lmw, lm_b, nullptr, tok, pos, 768, 768, DD, DD, 0,0,0);
  cls_k<<<BATCH,DD,0,stream>>>(cls_t, pos, tok);

  for (int i=0;i<3;i++) {
    // fused QKV -> (b,h,t,d) padded buffers
    gemm1w<M_QKV,false,false,true><<<dim3(MTOK/64,9,1),64,0,stream>>>(
        tok, weff + (size_t)i*576*192, effb + i*576, nullptr, qq, nullptr,
        192, 192, 0, 576, 0,0,0);
    vtrans_k<<<dim3(1024,4,8),64,0,stream>>>(vbuf, vt);
    // S = Q @ K^T (batched, padded 256x256), bf16 out
    gemm1w<M_BF16,false,false,false><<<dim3(4,4,1024),64,0,stream>>>(
        qq, kbuf, nullptr, nullptr, big, nullptr,
        DHP, DHP, TP, TP, (long)TP*DHP, (long)TP*DHP, (long)TP*TP);
    softmax_k<<<dim3(1024,50),256,0,stream>>>(big);
    // O = P @ V  (W operand = V^T), scatter to (b,t,192)
    gemm1w<M_PV,false,false,false><<<dim3(4,1,1024),64,0,stream>>>(
        big, vt, nullptr, nullptr, obuf, nullptr,
        TP, TP, 0, 48, (long)TP*TP, (long)DHP*TP, 0);
    // out-proj + residual (in-place into tok)
    gemm1w<M_BF16,false,true,true><<<dim3(MTOK/64,3,1),64,0,stream>>>(
        obuf, outw + (size_t)i*36864, out_b + i*192, tok, tok, nullptr,
        192, 192, DD, DD, 0,0,0);
    // MLP up + relu -> big
    gemm1w<M_BF16,true,false,true><<<dim3(MTOK/64,12,1),64,0,stream>>>(
        tok, upw + (size_t)i*147456, up_b + i*768, nullptr, big, nullptr,
        192, 192, 768, 768, 0,0,0);
    // MLP down -> tok (no residual, per reference)
    gemm1w<M_BF16,false,false,true><<<dim3(MTOK/64,3,1),64,0,stream>>>(
        big, dnw + (size_t)i*147456, dn_b + i*192, nullptr, tok, nullptr,
        768, 768, DD, DD, 0,0,0);
  }
  // head on cls rows (lda = 197*192), fp32 out
  gemm1w<M_F32,false,false,true><<<dim3(4,16,1),64,0,stream>>>(
      tok, hdw, head_b, nullptr, d_out, nullptr,
      192, 197*192, 1000, 1000, 0,0,0);
}

// Round 2
// 1372.215 us; speedup vs baseline: 1.0774x; 1.0774x over previous
//
#include <hip/hip_runtime.h>

typedef unsigned short u16;
typedef __bf16 bf16x8 __attribute__((ext_vector_type(8)));
typedef float  f32x4  __attribute__((ext_vector_type(4)));
typedef u16    u16x8  __attribute__((ext_vector_type(8)));

// ---------- problem constants ----------
#define BATCH 256
#define TT    197          // tokens
#define TP    256          // padded tokens (attention)
#define DD    192          // model dim
#define DHP   64           // padded head dim (real 48)
#define MTOK  (BATCH*TT)   // 50432 rows = 197*256
#define MPAT  (BATCH*196)  // 50176 rows = 196*256

constexpr size_t BIG_E  = 1024ull*256*256;   // S buffer (also patches 38.5M, mlp-h 38.7M)
constexpr size_t TOK_E  = (size_t)MTOK*DD;
constexpr size_t QKV_E  = 1024ull*TP*DHP;    // per q/k/v tensor
constexpr size_t VT_E   = 1024ull*DHP*TP;

__device__ __forceinline__ float b2f(u16 h){ union{unsigned u; float f;} x; x.u=(unsigned)h<<16; return x.f; }
__device__ __forceinline__ u16 f2b(float f){ union{float f; unsigned u;} x{f}; unsigned r = x.u + 0x7fffu + ((x.u>>16)&1u); return (u16)(r>>16); }

__device__ __forceinline__ void gload_lds16(const void* g, void* l) {
  __builtin_amdgcn_global_load_lds((__attribute__((address_space(1))) void*)(size_t)g,
                                   (__attribute__((address_space(3))) void*)l, 16, 0, 0);
}

// ---------- 4-wave 256x64-tile MFMA GEMM:  C = A(MxK) @ W(NxK)^T ----------
// Wave w computes rows [m0+w*64, m0+w*64+64); all waves share one 64-wide W tile.
enum { M_F32=0, M_BF16=1, M_QKV=2, M_PV=3, M_PATCH=4 };

template<int MODE, bool RELU, bool RES, bool BIAS>
__global__ __launch_bounds__(256)
void gemm4w(const u16* __restrict__ A, const u16* __restrict__ W,
            const float* __restrict__ bias, const u16* __restrict__ res,
            void* __restrict__ Cout, const float* __restrict__ aux,
            int K, int lda, int ldc, int Nreal,
            long bA, long bW, long bC)
{
  __shared__ __align__(16) u16 As[256*32];   // 16 KB
  __shared__ __align__(16) u16 Ws[64*32];    // 4 KB
  const int tid  = threadIdx.x;
  const int wv   = tid >> 6;
  const int lane = tid & 63;
  const int m0 = blockIdx.x * 256;
  const int n0 = blockIdx.y * 64;
  const int bz = blockIdx.z;
  const u16* Ab = A + (size_t)bz * (size_t)bA;
  const u16* Wb = W + (size_t)bz * (size_t)bW;

  const int lrow = lane & 15, quad = lane >> 4;
  const int srow = lane >> 2, sseg = lane & 3;   // staging: 16 rows x 4 x 16B per wave-issue

  f32x4 acc[4][4];
  #pragma unroll
  for (int i=0;i<4;i++)
    #pragma unroll
    for (int j=0;j<4;j++) { f32x4 z = {0.f,0.f,0.f,0.f}; acc[i][j] = z; }

  for (int k0 = 0; k0 < K; k0 += 32) {
    __syncthreads();
    // A tile: 256 rows x 32 cols; 4 issues, each wave stages rows [i*64+wv*16, +16)
    #pragma unroll
    for (int i=0;i<4;i++) {
      const u16* ga = Ab + (size_t)(m0 + i*64 + wv*16 + srow)*lda + (k0 + sseg*8);
      gload_lds16(ga, &As[(i*64 + wv*16)*32]);
    }
    // W tile: 64 rows x 32 cols; 1 issue, wave w stages rows [wv*16, +16)
    {
      const u16* gw = Wb + (size_t)(n0 + wv*16 + srow)*K + (k0 + sseg*8);
      gload_lds16(gw, &Ws[(wv*16)*32]);
    }
    __builtin_amdgcn_s_waitcnt(0);
    __syncthreads();
    bf16x8 af[4], wf[4];
    #pragma unroll
    for (int i=0;i<4;i++) {
      af[i] = *(const bf16x8*)&As[(wv*64 + i*16 + lrow)*32 + quad*8];
      wf[i] = *(const bf16x8*)&Ws[(i*16 + lrow)*32 + quad*8];
    }
    #pragma unroll
    for (int mi=0;mi<4;mi++)
      #pragma unroll
      for (int ni=0;ni<4;ni++)
        acc[mi][ni] = __builtin_amdgcn_mfma_f32_16x16x32_bf16(af[mi], wf[ni], acc[mi][ni], 0,0,0);
  }

  // epilogue: C/D layout col = lane&15, row = quad*4 + r
  #pragma unroll
  for (int mi=0;mi<4;mi++) {
    #pragma unroll
    for (int ni=0;ni<4;ni++) {
      #pragma unroll
      for (int r=0;r<4;r++) {
        int row = m0 + wv*64 + mi*16 + quad*4 + r;
        int col = n0 + ni*16 + lrow;
        float v = acc[mi][ni][r];
        if constexpr (MODE == M_F32) {
          if (col < Nreal) {
            if constexpr (BIAS) v += bias[col];
            ((float*)Cout)[(size_t)row*ldc + col] = v;
          }
        } else if constexpr (MODE == M_BF16) {
          if constexpr (BIAS) v += bias[col];
          if constexpr (RES)  v += b2f(res[(size_t)row*ldc + col]);
          if constexpr (RELU) v = v > 0.f ? v : 0.f;
          ((u16*)Cout)[(size_t)bz*(size_t)bC + (size_t)row*ldc + col] = f2b(v);
        } else if constexpr (MODE == M_QKV) {
          v += bias[col];
          int sel = col / 192, rem = col % 192;
          int h = rem / 48, d = rem % 48;
          int b = row / 197, t = row % 197;
          ((u16*)Cout)[(size_t)sel*QKV_E + ((size_t)(b*4 + h)*TP + t)*DHP + d] = f2b(v);
        } else if constexpr (MODE == M_PV) {
          if (col < 48 && row < 197) {
            int b = bz >> 2, h = bz & 3;
            ((u16*)Cout)[((size_t)(b*197) + row)*DD + h*48 + col] = f2b(v);
          }
        } else if constexpr (MODE == M_PATCH) {
          int b = row / 196, p = row % 196;
          v += bias[col] + aux[(size_t)(1 + p)*DD + col];
          ((u16*)Cout)[((size_t)(b*197) + 1 + p)*DD + col] = f2b(v);
        }
      }
    }
  }
}

// ---------- small kernels ----------
__global__ void cvt_k(const float* __restrict__ s, u16* __restrict__ d, int n) {
  int i = blockIdx.x*256 + threadIdx.x;
  if (i < n) d[i] = f2b(s[i]);
}

// im2col + fp32->bf16: patches[(b*196+pr*14+pc)*768 + c*256+i*16+j]
__global__ void im2col_k(const float* __restrict__ x, u16* __restrict__ P) {
  int id = blockIdx.x*256 + threadIdx.x;      // 256*3*224*28 threads exactly
  int w8 = id % 28; int r = id / 28;
  int h  = r % 224; r /= 224;
  int c  = r % 3;   int b = r / 3;
  const float* src = x + (((size_t)(b*3 + c)*224 + h)*224 + w8*8);
  float4 a  = *(const float4*)src;
  float4 bb = *(const float4*)(src + 4);
  int pr = h >> 4, i = h & 15, pc = (w8*8) >> 4, j0 = (w8*8) & 15;
  u16* dst = P + ((size_t)(b*196) + pr*14 + pc)*768 + (c*256 + i*16 + j0);
  u16x8 o;
  o[0]=f2b(a.x); o[1]=f2b(a.y); o[2]=f2b(a.z); o[3]=f2b(a.w);
  o[4]=f2b(bb.x); o[5]=f2b(bb.y); o[6]=f2b(bb.z); o[7]=f2b(bb.w);
  *(u16x8*)dst = o;
}

__global__ void cls_k(const float* __restrict__ cls_tok, const float* __restrict__ pos, u16* __restrict__ tok) {
  int b = blockIdx.x, d = threadIdx.x;
  tok[((size_t)b*197)*DD + d] = f2b(cls_tok[d] + pos[d]);
}

// W_eff[i][p*192+n][k] = sum_m in_w[i][p*192+n][m] * {q,k,v}_w[i][m][k]
__global__ void fusew_k(const float* __restrict__ in_w, const float* __restrict__ q_w,
                        const float* __restrict__ k_w, const float* __restrict__ v_w,
                        u16* __restrict__ weff) {
  int i = blockIdx.x, p = blockIdx.y, n = blockIdx.z;
  int k = threadIdx.x;
  const float* wrow = in_w + ((size_t)i*576 + p*192 + n)*192;
  const float* Bm = (p==0 ? q_w : (p==1 ? k_w : v_w)) + (size_t)i*192*192;
  float acc = 0.f;
  for (int m=0;m<192;m++) acc += wrow[m] * Bm[m*192 + k];
  weff[((size_t)i*576 + p*192 + n)*192 + k] = f2b(acc);
}

// b_eff[i][n] = sum_m in_w[i][n][m]*{q,k,v}_b[i][m] + in_b[i][n]
__global__ void fuseb_k(const float* __restrict__ in_w, const float* __restrict__ q_b,
                        const float* __restrict__ k_b, const float* __restrict__ v_b,
                        const float* __restrict__ in_b, float* __restrict__ effb) {
  int i = blockIdx.x, n = threadIdx.x;
  int p = n / 192;
  const float* bb = (p==0 ? q_b : (p==1 ? k_b : v_b)) + i*192;
  const float* wrow = in_w + ((size_t)i*576 + n)*192;
  float acc = in_b[i*576 + n];
  for (int m=0;m<192;m++) acc += wrow[m]*bb[m];
  effb[i*576 + n] = acc;
}

// V (1024,TP,DHP) -> Vt (1024,DHP,TP)
__global__ void vtrans_k(const u16* __restrict__ V, u16* __restrict__ Vt) {
  int bz = blockIdx.x, tc = blockIdx.y, dq = blockIdx.z;
  int t = tc*64 + threadIdx.x;
  if (t >= 197) return;
  u16x8 val = *(const u16x8*)(V + ((size_t)bz*TP + t)*DHP + dq*8);
  u16* dst = Vt + (size_t)bz*DHP*TP + (size_t)(dq*8)*TP + t;
  #pragma unroll
  for (int j=0;j<8;j++) dst[(size_t)j*TP] = val[j];
}

// softmax over k (<197) with scale folded in; zero cols 197..255; wave per row
__global__ void softmax_k(u16* __restrict__ S) {
  int bz = blockIdx.x;
  int wave = threadIdx.x >> 6, lane = threadIdx.x & 63;
  int t = blockIdx.y*4 + wave;
  if (t >= 197) return;
  u16* row = S + ((size_t)bz*TP + t)*TP;
  const float scale = 0.14433756729740643f;   // 1/sqrt(48)
  float v[4];
  #pragma unroll
  for (int j=0;j<4;j++) {
    int c = lane + j*64;
    v[j] = (c < 197) ? b2f(row[c]) : -1e30f;
  }
  float mx = fmaxf(fmaxf(v[0],v[1]), fmaxf(v[2],v[3]));
  #pragma unroll
  for (int s=32; s; s>>=1) mx = fmaxf(mx, __shfl_xor(mx, s, 64));
  float e[4]; float sum = 0.f;
  #pragma unroll
  for (int j=0;j<4;j++) {
    int c = lane + j*64;
    e[j] = (c < 197) ? __expf((v[j]-mx)*scale) : 0.f;
    sum += e[j];
  }
  #pragma unroll
  for (int s=32; s; s>>=1) sum += __shfl_xor(sum, s, 64);
  float inv = 1.f / sum;
  #pragma unroll
  for (int j=0;j<4;j++) row[lane + j*64] = f2b(e[j]*inv);
}

// ---------- orchestration ----------
extern "C" void kernel_launch(void* const* d_in, const int* in_sizes, int n_in,
                              void* d_out, int out_size, void* d_ws, size_t ws_size,
                              hipStream_t stream) {
  const float* x      = (const float*)d_in[0];
  const float* lm_w   = (const float*)d_in[1];
  const float* lm_b   = (const float*)d_in[2];
  const float* cls_t  = (const float*)d_in[3];
  const float* pos    = (const float*)d_in[4];
  const float* q_w    = (const float*)d_in[5];
  const float* q_b    = (const float*)d_in[6];
  const float* k_w    = (const float*)d_in[7];
  const float* k_b    = (const float*)d_in[8];
  const float* v_w    = (const float*)d_in[9];
  const float* v_b    = (const float*)d_in[10];
  const float* in_w   = (const float*)d_in[11];
  const float* in_b   = (const float*)d_in[12];
  const float* out_w  = (const float*)d_in[13];
  const float* out_b  = (const float*)d_in[14];
  const float* up_w   = (const float*)d_in[15];
  const float* up_b   = (const float*)d_in[16];
  const float* dn_w   = (const float*)d_in[17];
  const float* dn_b   = (const float*)d_in[18];
  const float* head_w = (const float*)d_in[19];
  const float* head_b = (const float*)d_in[20];

  char* ws = (char*)d_ws;
  size_t off = 0;
  auto alloc = [&](size_t elems, size_t esz) {
    void* p = ws + off; off += ((elems*esz + 255)/256)*256; return p;
  };
  u16*  big  = (u16*)alloc(BIG_E, 2);        // patches / S / mlp hidden
  u16*  tok  = (u16*)alloc(TOK_E, 2);
  u16*  qq   = (u16*)alloc(QKV_E*3, 2);      // q,k,v contiguous
  u16*  vt   = (u16*)alloc(VT_E, 2);
  u16*  obuf = (u16*)alloc(TOK_E, 2);
  u16*  lmw  = (u16*)alloc(147456, 2);
  u16*  outw = (u16*)alloc(110592, 2);
  u16*  upw  = (u16*)alloc(442368, 2);
  u16*  dnw  = (u16*)alloc(442368, 2);
  u16*  hdw  = (u16*)alloc(196608, 2);       // head_w padded to 1024 rows
  u16*  weff = (u16*)alloc(331776, 2);
  float* effb = (float*)alloc(1728, 4);
  (void)ws_size; (void)in_sizes; (void)n_in; (void)out_size;

  u16* kbuf = qq + QKV_E;
  u16* vbuf = qq + 2*QKV_E;

  // weight prep
  cvt_k<<<(147456+255)/256,256,0,stream>>>(lm_w,  lmw, 147456);
  cvt_k<<<(110592+255)/256,256,0,stream>>>(out_w, outw, 110592);
  cvt_k<<<(442368+255)/256,256,0,stream>>>(up_w,  upw, 442368);
  cvt_k<<<(442368+255)/256,256,0,stream>>>(dn_w,  dnw, 442368);
  cvt_k<<<(192000+255)/256,256,0,stream>>>(head_w,hdw, 192000);
  hipMemsetAsync(hdw + 192000, 0, (196608-192000)*2, stream);
  fusew_k<<<dim3(3,3,192),192,0,stream>>>(in_w, q_w, k_w, v_w, weff);
  fuseb_k<<<3,576,0,stream>>>(in_w, q_b, k_b, v_b, in_b, effb);

  // patch embed + pos + cls
  im2col_k<<<18816,256,0,stream>>>(x, big);
  gemm4w<M_PATCH,false,false,true><<<dim3(MPAT/256,3,1),256,0,stream>>>(
      big, lmw, lm_b, nullptr, tok, pos, 768, 768, DD, DD, 0,0,0);
  cls_k<<<BATCH,DD,0,stream>>>(cls_t, pos, tok);

  for (int i=0;i<3;i++) {
    // fused QKV -> (b,h,t,d) padded buffers
    gemm4w<M_QKV,false,false,true><<<dim3(MTOK/256,9,1),256,0,stream>>>(
        tok, weff + (size_t)i*576*192, effb + i*576, nullptr, qq, nullptr,
        192, 192, 0, 576, 0,0,0);
    vtrans_k<<<dim3(1024,4,8),64,0,stream>>>(vbuf, vt);
    // S = Q @ K^T (batched, padded 256x256), bf16 out
    gemm4w<M_BF16,false,false,false><<<dim3(1,4,1024),256,0,stream>>>(
        qq, kbuf, nullptr, nullptr, big, nullptr,
        DHP, DHP, TP, TP, (long)TP*DHP, (long)TP*DHP, (long)TP*TP);
    softmax_k<<<dim3(1024,50),256,0,stream>>>(big);
    // O = P @ V  (W operand = V^T), scatter to (b,t,192)
    gemm4w<M_PV,false,false,false><<<dim3(1,1,1024),256,0,stream>>>(
        big, vt, nullptr, nullptr, obuf, nullptr,
        TP, TP, 0, 48, (long)TP*TP, (long)DHP*TP, 0);
    // out-proj + residual (in-place into tok)
    gemm4w<M_BF16,false,true,true><<<dim3(MTOK/256,3,1),256,0,stream>>>(
        obuf, outw + (size_t)i*36864, out_b + i*192, tok, tok, nullptr,
        192, 192, DD, DD, 0,0,0);
    // MLP up + relu -> big
    gemm4w<M_BF16,true,false,true><<<dim3(MTOK/256,12,1),256,0,stream>>>(
        tok, upw + (size_t)i*147456, up_b + i*768, nullptr, big, nullptr,
        192, 192, 768, 768, 0,0,0);
    // MLP down -> tok (no residual, per reference)
    gemm4w<M_BF16,false,false,true><<<dim3(MTOK/256,3,1),256,0,stream>>>(
        big, dnw + (size_t)i*147456, dn_b + i*192, nullptr, tok, nullptr,
        768, 768, DD, DD, 0,0,0);
  }
  // head on cls rows (lda = 197*192), fp32 out
  gemm4w<M_F32,false,false,true><<<dim3(1,16,1),256,0,stream>>>(
      tok, hdw, head_b, nullptr, d_out, nullptr,
      192, 197*192, 1000, 1000, 0,0,0);
}

// Round 3
// 1147.246 us; speedup vs baseline: 1.2886x; 1.1961x over previous
//
#include <hip/hip_runtime.h>

typedef unsigned short u16;
typedef __bf16 bf16x8 __attribute__((ext_vector_type(8)));
typedef float  f32x4  __attribute__((ext_vector_type(4)));
typedef u16    u16x8  __attribute__((ext_vector_type(8)));

// ---------- problem constants ----------
#define BATCH 256
#define TT    197          // tokens
#define TP    256          // padded tokens
#define DD    192          // model dim
#define DHP   64           // padded head dim (real 48)
#define MTOK  (BATCH*TT)   // 50432 rows = 197*256
#define MPAT  (BATCH*196)  // 50176 rows

constexpr size_t BIG_E  = 1024ull*256*256;   // patches 38.5M / mlp-h 38.7M
constexpr size_t TOK_E  = (size_t)MTOK*DD;
constexpr size_t QKV_E  = 1024ull*TP*DHP;    // per q/k/v tensor (padded)

__device__ __forceinline__ float b2f(u16 h){ union{unsigned u; float f;} x; x.u=(unsigned)h<<16; return x.f; }
__device__ __forceinline__ u16 f2b(float f){ union{float f; unsigned u;} x{f}; unsigned r = x.u + 0x7fffu + ((x.u>>16)&1u); return (u16)(r>>16); }
__device__ __forceinline__ bf16x8 as_bf(u16x8 v){ return __builtin_bit_cast(bf16x8, v); }

__device__ __forceinline__ void gload_lds16(const void* g, void* l) {
  __builtin_amdgcn_global_load_lds((__attribute__((address_space(1))) void*)(size_t)g,
                                   (__attribute__((address_space(3))) void*)l, 16, 0, 0);
}

// ---------- 4-wave 256x64-tile MFMA GEMM:  C = A(MxK) @ W(NxK)^T ----------
enum { M_F32=0, M_BF16=1, M_QKV=2, M_PATCH=4 };

template<int MODE, bool RELU, bool RES, bool BIAS>
__global__ __launch_bounds__(256)
void gemm4w(const u16* __restrict__ A, const u16* __restrict__ W,
            const float* __restrict__ bias, const u16* __restrict__ res,
            void* __restrict__ Cout, const float* __restrict__ aux,
            int K, int lda, int ldc, int Nreal,
            long bA, long bW, long bC)
{
  __shared__ __align__(16) u16 As[256*32];   // 16 KB
  __shared__ __align__(16) u16 Ws[64*32];    // 4 KB
  const int tid  = threadIdx.x;
  const int wv   = tid >> 6;
  const int lane = tid & 63;
  const int m0 = blockIdx.x * 256;
  const int n0 = blockIdx.y * 64;
  const int bz = blockIdx.z;
  const u16* Ab = A + (size_t)bz * (size_t)bA;
  const u16* Wb = W + (size_t)bz * (size_t)bW;

  const int lrow = lane & 15, quad = lane >> 4;
  const int srow = lane >> 2, sseg = lane & 3;

  f32x4 acc[4][4];
  #pragma unroll
  for (int i=0;i<4;i++)
    #pragma unroll
    for (int j=0;j<4;j++) { f32x4 z = {0.f,0.f,0.f,0.f}; acc[i][j] = z; }

  for (int k0 = 0; k0 < K; k0 += 32) {
    __syncthreads();
    #pragma unroll
    for (int i=0;i<4;i++) {
      const u16* ga = Ab + (size_t)(m0 + i*64 + wv*16 + srow)*lda + (k0 + sseg*8);
      gload_lds16(ga, &As[(i*64 + wv*16)*32]);
    }
    {
      const u16* gw = Wb + (size_t)(n0 + wv*16 + srow)*K + (k0 + sseg*8);
      gload_lds16(gw, &Ws[(wv*16)*32]);
    }
    __builtin_amdgcn_s_waitcnt(0);
    __syncthreads();
    bf16x8 af[4], wf[4];
    #pragma unroll
    for (int i=0;i<4;i++) {
      af[i] = *(const bf16x8*)&As[(wv*64 + i*16 + lrow)*32 + quad*8];
      wf[i] = *(const bf16x8*)&Ws[(i*16 + lrow)*32 + quad*8];
    }
    #pragma unroll
    for (int mi=0;mi<4;mi++)
      #pragma unroll
      for (int ni=0;ni<4;ni++)
        acc[mi][ni] = __builtin_amdgcn_mfma_f32_16x16x32_bf16(af[mi], wf[ni], acc[mi][ni], 0,0,0);
  }

  #pragma unroll
  for (int mi=0;mi<4;mi++) {
    #pragma unroll
    for (int ni=0;ni<4;ni++) {
      #pragma unroll
      for (int r=0;r<4;r++) {
        int row = m0 + wv*64 + mi*16 + quad*4 + r;
        int col = n0 + ni*16 + lrow;
        float v = acc[mi][ni][r];
        if constexpr (MODE == M_F32) {
          if (col < Nreal) {
            if constexpr (BIAS) v += bias[col];
            ((float*)Cout)[(size_t)row*ldc + col] = v;
          }
        } else if constexpr (MODE == M_BF16) {
          if constexpr (BIAS) v += bias[col];
          if constexpr (RES)  v += b2f(res[(size_t)row*ldc + col]);
          if constexpr (RELU) v = v > 0.f ? v : 0.f;
          ((u16*)Cout)[(size_t)bz*(size_t)bC + (size_t)row*ldc + col] = f2b(v);
        } else if constexpr (MODE == M_QKV) {
          v += bias[col];
          int sel = col / 192, rem = col % 192;
          int h = rem / 48, d = rem % 48;
          int b = row / 197, t = row % 197;
          ((u16*)Cout)[(size_t)sel*QKV_E + ((size_t)(b*4 + h)*TP + t)*DHP + d] = f2b(v);
        } else if constexpr (MODE == M_PATCH) {
          int b = row / 196, p = row % 196;
          v += bias[col] + aux[(size_t)(1 + p)*DD + col];
          ((u16*)Cout)[((size_t)(b*197) + 1 + p)*DD + col] = f2b(v);
        }
      }
    }
  }
}

// ---------- fused flash attention: one workgroup per (b,h) ----------
// LDS: K 208x72 (d-pad zeroed), Vt 49x216, P 4x16x72. 60.3 KB total.
#define KSTR 72
#define VSTR 216
#define PSTR 72
#define TKR  208

__global__ __launch_bounds__(256,1)
void flash_k(const u16* __restrict__ Qg, const u16* __restrict__ Kg,
             const u16* __restrict__ Vg, u16* __restrict__ Og)
{
  __shared__ __align__(16) u16 Ks[TKR*KSTR];
  __shared__ __align__(16) u16 Vs[49*VSTR];
  __shared__ __align__(16) u16 Ps[4*16*PSTR];
  const int bh = blockIdx.x;
  const int b = bh >> 2, h = bh & 3;
  const int tid = threadIdx.x, wv = tid >> 6, lane = tid & 63;
  const int lrow = lane & 15, quad = lane >> 4;
  const size_t base = (size_t)bh * TP * DHP;
  const float scale = 0.14433756729740643f;   // 1/sqrt(48)

  // Q fragments (A-layout): t = wv*64 + rg*16 + lrow, k(d) = ka*32 + quad*8
  bf16x8 qf[4][2];
  #pragma unroll
  for (int rg=0; rg<4; rg++)
    #pragma unroll
    for (int ka=0; ka<2; ka++)
      qf[rg][ka] = as_bf(*(const u16x8*)(Qg + base + (size_t)(wv*64+rg*16+lrow)*DHP + ka*32 + quad*8));

  // stage K rows 0..207: segs 0..5 = data, segs 6..7 = zeros (d pad)
  for (int it=0; it<5; it++) {
    int slot = it*256 + tid;
    if (slot < 1248) {
      int t = slot/6, sg = slot - t*6;
      u16x8 v = *(const u16x8*)(Kg + base + (size_t)t*DHP + sg*8);
      *(u16x8*)&Ks[t*KSTR + sg*8] = v;
    }
  }
  {
    u16x8 z = {0,0,0,0,0,0,0,0};
    for (int it=0; it<2; it++) {
      int slot = it*256 + tid;
      if (slot < 416) { int t = slot>>1, sg = 6 + (slot&1);
        *(u16x8*)&Ks[t*KSTR + sg*8] = z; }
    }
  }
  // stage V transposed: Vs[d][t], d<48, t<208
  for (int it=0; it<5; it++) {
    int slot = it*256 + tid;
    if (slot < 1248) {
      int sg = slot/208, t = slot - sg*208;
      u16x8 v = *(const u16x8*)(Vg + base + (size_t)t*DHP + sg*8);
      #pragma unroll
      for (int j=0;j<8;j++) Vs[(sg*8+j)*VSTR + t] = v[j];
    }
  }
  __syncthreads();

  f32x4 o[4][3];
  float m_i[4][4], l_i[4][4];
  #pragma unroll
  for (int rg=0;rg<4;rg++) {
    #pragma unroll
    for (int dg=0;dg<3;dg++) { f32x4 z = {0.f,0.f,0.f,0.f}; o[rg][dg] = z; }
    #pragma unroll
    for (int r=0;r<4;r++) { m_i[rg][r] = -1e30f; l_i[rg][r] = 0.f; }
  }
  u16* Pw = &Ps[wv*16*PSTR];

  #pragma unroll
  for (int c=0; c<4; c++) {
    const int NC = (c<3) ? 4 : 1;     // chunk 3: only cols 192..207 can be valid
    f32x4 s[4][4];
    #pragma unroll
    for (int rg=0;rg<4;rg++)
      #pragma unroll
      for (int cg=0;cg<4;cg++) if (cg < NC) { f32x4 z = {0.f,0.f,0.f,0.f}; s[rg][cg] = z; }

    // S chunk = Q @ K^T
    #pragma unroll
    for (int cg=0;cg<4;cg++) if (cg < NC) {
      #pragma unroll
      for (int ka=0; ka<2; ka++) {
        bf16x8 kf = as_bf(*(const u16x8*)&Ks[(c*64+cg*16+lrow)*KSTR + ka*32 + quad*8]);
        #pragma unroll
        for (int rg=0;rg<4;rg++)
          s[rg][cg] = __builtin_amdgcn_mfma_f32_16x16x32_bf16(qf[rg][ka], kf, s[rg][cg], 0,0,0);
      }
    }

    // online softmax + PV, per row-group
    #pragma unroll
    for (int rg=0;rg<4;rg++) {
      if (c == 3) {
        #pragma unroll
        for (int r=0;r<4;r++) s[rg][0][r] = (lrow >= 5) ? -1e30f : s[rg][0][r];
      }
      float mnew[4], al[4];
      #pragma unroll
      for (int r=0;r<4;r++) {
        float mc = s[rg][0][r];
        #pragma unroll
        for (int cg=1;cg<4;cg++) if (cg < NC) mc = fmaxf(mc, s[rg][cg][r]);
        #pragma unroll
        for (int sh=1; sh<16; sh<<=1) mc = fmaxf(mc, __shfl_xor(mc, sh, 64));
        float mo = m_i[rg][r];
        float mn = fmaxf(mo, mc);
        mnew[r] = mn;
        al[r] = __expf((mo - mn)*scale);
      }
      #pragma unroll
      for (int r=0;r<4;r++) {
        float acc = 0.f;
        #pragma unroll
        for (int cg=0;cg<4;cg++) if (cg < NC) {
          float p = __expf((s[rg][cg][r] - mnew[r])*scale);
          s[rg][cg][r] = p;
          acc += p;
        }
        #pragma unroll
        for (int sh=1; sh<16; sh<<=1) acc += __shfl_xor(acc, sh, 64);
        l_i[rg][r] = l_i[rg][r]*al[r] + acc;
        m_i[rg][r] = mnew[r];
      }
      #pragma unroll
      for (int dg=0;dg<3;dg++)
        #pragma unroll
        for (int r=0;r<4;r++) o[rg][dg][r] *= al[r];

      // P (C-layout) -> LDS (row-major) for A-layout reads
      #pragma unroll
      for (int cg=0;cg<4;cg++) if (cg < NC) {
        #pragma unroll
        for (int r=0;r<4;r++)
          Pw[(quad*4+r)*PSTR + cg*16 + lrow] = f2b(s[rg][cg][r]);
      }
      if (c == 3) {
        #pragma unroll
        for (int r=0;r<4;r++) Pw[(quad*4+r)*PSTR + 16 + lrow] = 0;
      }
      __builtin_amdgcn_s_waitcnt(0xC07F);   // lgkmcnt(0)

      const int NK = (c<3) ? 2 : 1;
      #pragma unroll
      for (int ka=0; ka<2; ka++) if (ka < NK) {
        bf16x8 pf = as_bf(*(const u16x8*)&Pw[lrow*PSTR + ka*32 + quad*8]);
        #pragma unroll
        for (int dg=0;dg<3;dg++) {
          bf16x8 vf = as_bf(*(const u16x8*)&Vs[(dg*16+lrow)*VSTR + c*64 + ka*32 + quad*8]);
          o[rg][dg] = __builtin_amdgcn_mfma_f32_16x16x32_bf16(pf, vf, o[rg][dg], 0,0,0);
        }
      }
      __builtin_amdgcn_s_waitcnt(0xC07F);   // drain reads before next rg overwrites Pw
    }
  }

  // epilogue: O /= l, store rows t<197, cols d<48
  #pragma unroll
  for (int rg=0;rg<4;rg++) {
    #pragma unroll
    for (int r=0;r<4;r++) {
      int t = wv*64 + rg*16 + quad*4 + r;
      if (t < 197) {
        float inv = 1.0f / l_i[rg][r];
        u16* dst = Og + ((size_t)(b*197) + t)*DD + h*48;
        #pragma unroll
        for (int dg=0;dg<3;dg++) dst[dg*16 + lrow] = f2b(o[rg][dg][r]*inv);
      }
    }
  }
}

// ---------- small kernels ----------
// all weight fp32->bf16 conversions in one launch (incl. head pad-to-zero)
__global__ void cvt5_k(const float* __restrict__ a, const float* __restrict__ b,
                       const float* __restrict__ c, const float* __restrict__ d,
                       const float* __restrict__ e,
                       u16* __restrict__ oa, u16* __restrict__ ob, u16* __restrict__ oc,
                       u16* __restrict__ od, u16* __restrict__ oe) {
  int i = blockIdx.x*256 + threadIdx.x;
  if (i < 147456) { oa[i] = f2b(a[i]); return; } i -= 147456;
  if (i < 110592) { ob[i] = f2b(b[i]); return; } i -= 110592;
  if (i < 442368) { oc[i] = f2b(c[i]); return; } i -= 442368;
  if (i < 442368) { od[i] = f2b(d[i]); return; } i -= 442368;
  if (i < 196608) { oe[i] = (i < 192000) ? f2b(e[i]) : (u16)0; }
}

__global__ void im2col_k(const float* __restrict__ x, u16* __restrict__ P) {
  int id = blockIdx.x*256 + threadIdx.x;
  int w8 = id % 28; int r = id / 28;
  int h  = r % 224; r /= 224;
  int c  = r % 3;   int b = r / 3;
  const float* src = x + (((size_t)(b*3 + c)*224 + h)*224 + w8*8);
  float4 a  = *(const float4*)src;
  float4 bb = *(const float4*)(src + 4);
  int pr = h >> 4, i = h & 15, pc = (w8*8) >> 4, j0 = (w8*8) & 15;
  u16* dst = P + ((size_t)(b*196) + pr*14 + pc)*768 + (c*256 + i*16 + j0);
  u16x8 o;
  o[0]=f2b(a.x); o[1]=f2b(a.y); o[2]=f2b(a.z); o[3]=f2b(a.w);
  o[4]=f2b(bb.x); o[5]=f2b(bb.y); o[6]=f2b(bb.z); o[7]=f2b(bb.w);
  *(u16x8*)dst = o;
}

__global__ void cls_k(const float* __restrict__ cls_tok, const float* __restrict__ pos, u16* __restrict__ tok) {
  int b = blockIdx.x, d = threadIdx.x;
  tok[((size_t)b*197)*DD + d] = f2b(cls_tok[d] + pos[d]);
}

__global__ void fusew_k(const float* __restrict__ in_w, const float* __restrict__ q_w,
                        const float* __restrict__ k_w, const float* __restrict__ v_w,
                        u16* __restrict__ weff) {
  int i = blockIdx.x, p = blockIdx.y, n = blockIdx.z;
  int k = threadIdx.x;
  const float* wrow = in_w + ((size_t)i*576 + p*192 + n)*192;
  const float* Bm = (p==0 ? q_w : (p==1 ? k_w : v_w)) + (size_t)i*192*192;
  float acc = 0.f;
  for (int m=0;m<192;m++) acc += wrow[m] * Bm[m*192 + k];
  weff[((size_t)i*576 + p*192 + n)*192 + k] = f2b(acc);
}

__global__ void fuseb_k(const float* __restrict__ in_w, const float* __restrict__ q_b,
                        const float* __restrict__ k_b, const float* __restrict__ v_b,
                        const float* __restrict__ in_b, float* __restrict__ effb) {
  int i = blockIdx.x, n = threadIdx.x;
  int p = n / 192;
  const float* bb = (p==0 ? q_b : (p==1 ? k_b : v_b)) + i*192;
  const float* wrow = in_w + ((size_t)i*576 + n)*192;
  float acc = in_b[i*576 + n];
  for (int m=0;m<192;m++) acc += wrow[m]*bb[m];
  effb[i*576 + n] = acc;
}

// ---------- orchestration ----------
extern "C" void kernel_launch(void* const* d_in, const int* in_sizes, int n_in,
                              void* d_out, int out_size, void* d_ws, size_t ws_size,
                              hipStream_t stream) {
  const float* x      = (const float*)d_in[0];
  const float* lm_w   = (const float*)d_in[1];
  const float* lm_b   = (const float*)d_in[2];
  const float* cls_t  = (const float*)d_in[3];
  const float* pos    = (const float*)d_in[4];
  const float* q_w    = (const float*)d_in[5];
  const float* q_b    = (const float*)d_in[6];
  const float* k_w    = (const float*)d_in[7];
  const float* k_b    = (const float*)d_in[8];
  const float* v_w    = (const float*)d_in[9];
  const float* v_b    = (const float*)d_in[10];
  const float* in_w   = (const float*)d_in[11];
  const float* in_b   = (const float*)d_in[12];
  const float* out_w  = (const float*)d_in[13];
  const float* out_b  = (const float*)d_in[14];
  const float* up_w   = (const float*)d_in[15];
  const float* up_b   = (const float*)d_in[16];
  const float* dn_w   = (const float*)d_in[17];
  const float* dn_b   = (const float*)d_in[18];
  const float* head_w = (const float*)d_in[19];
  const float* head_b = (const float*)d_in[20];

  char* ws = (char*)d_ws;
  size_t off = 0;
  auto alloc = [&](size_t elems, size_t esz) {
    void* p = ws + off; off += ((elems*esz + 255)/256)*256; return p;
  };
  u16*  big  = (u16*)alloc(BIG_E, 2);        // patches / mlp hidden
  u16*  tok  = (u16*)alloc(TOK_E, 2);
  u16*  qq   = (u16*)alloc(QKV_E*3, 2);      // q,k,v contiguous (b,h,t,d) padded
  u16*  obuf = (u16*)alloc(TOK_E, 2);
  u16*  lmw  = (u16*)alloc(147456, 2);
  u16*  outw = (u16*)alloc(110592, 2);
  u16*  upw  = (u16*)alloc(442368, 2);
  u16*  dnw  = (u16*)alloc(442368, 2);
  u16*  hdw  = (u16*)alloc(196608, 2);
  u16*  weff = (u16*)alloc(331776, 2);
  float* effb = (float*)alloc(1728, 4);
  (void)ws_size; (void)in_sizes; (void)n_in; (void)out_size;

  u16* kbuf = qq + QKV_E;
  u16* vbuf = qq + 2*QKV_E;

  // weight prep (one launch) + QKV weight fusion
  cvt5_k<<<(1339392+255)/256,256,0,stream>>>(lm_w, out_w, up_w, dn_w, head_w,
                                             lmw, outw, upw, dnw, hdw);
  fusew_k<<<dim3(3,3,192),192,0,stream>>>(in_w, q_w, k_w, v_w, weff);
  fuseb_k<<<3,576,0,stream>>>(in_w, q_b, k_b, v_b, in_b, effb);

  // patch embed + pos + cls
  im2col_k<<<18816,256,0,stream>>>(x, big);
  gemm4w<M_PATCH,false,false,true><<<dim3(MPAT/256,3,1),256,0,stream>>>(
      big, lmw, lm_b, nullptr, tok, pos, 768, 768, DD, DD, 0,0,0);
  cls_k<<<BATCH,DD,0,stream>>>(cls_t, pos, tok);

  for (int i=0;i<3;i++) {
    gemm4w<M_QKV,false,false,true><<<dim3(MTOK/256,9,1),256,0,stream>>>(
        tok, weff + (size_t)i*576*192, effb + i*576, nullptr, qq, nullptr,
        192, 192, 0, 576, 0,0,0);
    flash_k<<<1024,256,0,stream>>>(qq, kbuf, vbuf, obuf);
    gemm4w<M_BF16,false,true,true><<<dim3(MTOK/256,3,1),256,0,stream>>>(
        obuf, outw + (size_t)i*36864, out_b + i*192, tok, tok, nullptr,
        192, 192, DD, DD, 0,0,0);
    gemm4w<M_BF16,true,false,true><<<dim3(MTOK/256,12,1),256,0,stream>>>(
        tok, upw + (size_t)i*147456, up_b + i*768, nullptr, big, nullptr,
        192, 192, 768, 768, 0,0,0);
    gemm4w<M_BF16,false,false,true><<<dim3(MTOK/256,3,1),256,0,stream>>>(
        big, dnw + (size_t)i*147456, dn_b + i*192, nullptr, tok, nullptr,
        768, 768, DD, DD, 0,0,0);
  }
  gemm4w<M_F32,false,false,true><<<dim3(1,16,1),256,0,stream>>>(
      tok, hdw, head_b, nullptr, d_out, nullptr,
      192, 197*192, 1000, 1000, 0,0,0);
}